// Round 1
// baseline (2452.825 us; speedup 1.0000x reference)
//
#include <hip/hip_runtime.h>
#include <math.h>

#define NB 8
#define NC 192
#define DIN 384
#define NL 3136
#define ROWS (NB*NL)     // 25088
#define NE 6160
#define NHID 768

typedef unsigned short u16;
typedef unsigned int u32;
typedef unsigned long long u64;

// ---------- helpers ----------
__device__ __forceinline__ float wredsum(float v){
  v += __shfl_xor(v, 1, 64); v += __shfl_xor(v, 2, 64); v += __shfl_xor(v, 4, 64);
  v += __shfl_xor(v, 8, 64); v += __shfl_xor(v, 16, 64); v += __shfl_xor(v, 32, 64);
  return v;
}
__device__ __forceinline__ void edge_decode(int e, int& u, int& v){
  if (e < 3080){ int h = e/55, w = e - h*55; u = h*56 + w; v = u + 1; }
  else { int e2 = e - 3080; int h = e2/56, w = e2 - h*56; u = h*56 + w; v = u + 56; }
}
__device__ __forceinline__ float siluf(float x){ return x / (1.0f + expf(-x)); }
__device__ __forceinline__ float sofplus(float x){ return fmaxf(x, 0.0f) + log1pf(expf(-fabsf(x))); }
__device__ __forceinline__ float geluf(float x){ return 0.5f * x * (1.0f + erff(x * 0.70710678118654752f)); }

// ---------- node norms (wave per node) ----------
__global__ __launch_bounds__(256) void norms_kernel(const float* __restrict__ x, float* __restrict__ nrm){
  int gw = (int)((blockIdx.x * 256u + threadIdx.x) >> 6);
  int lane = threadIdx.x & 63;
  if (gw >= ROWS) return;
  const float* r = x + (size_t)gw * NC;
  float s = 0.f;
#pragma unroll
  for (int j = 0; j < 3; ++j){ float v = r[lane + 64*j]; s += v*v; }
  s = wredsum(s);
  if (lane == 0) nrm[gw] = sqrtf(s) + 1e-8f;
}

// ---------- edge keys (wave per edge) ----------
__global__ __launch_bounds__(256) void keys_kernel(const float* __restrict__ x, const float* __restrict__ nrm,
                                                   u64* __restrict__ keys){
  int gw = (int)((blockIdx.x * 256u + threadIdx.x) >> 6);
  int lane = threadIdx.x & 63;
  if (gw >= NB * NE) return;
  int b = gw / NE, e = gw - b * NE;
  int u, v; edge_decode(e, u, v);
  const float* ru = x + ((size_t)b * NL + u) * NC;
  const float* rv = x + ((size_t)b * NL + v) * NC;
  float s = 0.f;
#pragma unroll
  for (int j = 0; j < 3; ++j){ s += ru[lane + 64*j] * rv[lane + 64*j]; }
  s = wredsum(s);
  if (lane == 0){
    float cosv = s / (nrm[b*NL + u] * nrm[b*NL + v]);
    float wgt = expf(1.0f - cosv);
    keys[(size_t)b*NE + e] = ((u64)__float_as_uint(wgt) << 32) | (u64)(u32)e;
  }
}

// ---------- per-image: Boruvka MST + CSR + BFS levels ----------
__global__ __launch_bounds__(1024) void tree_kernel(const u64* __restrict__ keys_g,
      int* __restrict__ order_g, int* __restrict__ parpos_g,
      int* __restrict__ lvl_g, int* __restrict__ nlev_g){
  __shared__ __align__(16) char sm[62736];
  const int b = blockIdx.x;
  const int t = threadIdx.x;
  const int NT = 1024;
  u64* best   = (u64*)sm;            // [3136]  (phase B)
  u16* parent = (u16*)(sm + 25088);
  u16* comp   = (u16*)(sm + 31360);
  u16* mstU   = (u16*)(sm + 37632);
  u16* mstV   = (u16*)(sm + 43904);
  u16* adjl   = (u16*)(sm + 50176);  // [6270]
  u32* cnts   = (u32*)(sm + 62720);  // [4]
  // phase C/D aliases (over dead regions)
  u32* deg    = (u32*)sm;            // [3136]
  u32* offA   = (u32*)(sm + 12544);  // [3137]
  u32* aux    = (u32*)(sm + 25096);  // [1024]
  u16* bfs    = (u16*)sm;            // [3136] (phase D)
  u16* ppos   = (u16*)(sm + 6272);   // [3136]
  u16* posOf  = (u16*)(sm + 29192);  // [3136]

  const u64* kb = keys_g + (size_t)b * NE;
  for (int v = t; v < NL; v += NT) parent[v] = (u16)v;
  if (t == 0) cnts[0] = 0;
  __syncthreads();

  for (int round = 0; round < 24; ++round){
    for (int it = 0; it < 12; ++it){
      for (int v = t; v < NL; v += NT) parent[v] = parent[parent[v]];
      __syncthreads();
    }
    for (int v = t; v < NL; v += NT){ comp[v] = parent[v]; best[v] = ~0ull; }
    if (t == 0) cnts[2] = 0;
    __syncthreads();
    for (int e = t; e < NE; e += NT){
      int u, v; edge_decode(e, u, v);
      u16 ru = comp[u], rv = comp[v];
      if (ru != rv){
        u64 k = kb[e];
        atomicMin(&best[ru], k);
        atomicMin(&best[rv], k);
      }
    }
    __syncthreads();
    for (int r = t; r < NL; r += NT){
      if (comp[r] == (u16)r){
        u64 bk = best[r];
        if (bk != ~0ull){
          int e = (int)(u32)bk; int u, v; edge_decode(e, u, v);
          u16 ru = comp[u], rv = comp[v];
          u16 other = (ru == (u16)r) ? rv : ru;
          bool mutual = (best[other] == bk);
          if (!mutual || (u16)r < other){
            parent[r] = other;
            u32 id = atomicAdd(&cnts[0], 1);
            mstU[id] = (u16)u; mstV[id] = (u16)v;
            cnts[2] = 1;
          }
        }
      }
    }
    __syncthreads();
    if (cnts[0] >= (u32)(NL - 1) || cnts[2] == 0) break;
  }
  __syncthreads();

  // CSR adjacency of MST
  const int nm = NL - 1;
  for (int v = t; v < NL; v += NT) deg[v] = 0;
  __syncthreads();
  for (int i = t; i < nm; i += NT){ atomicAdd(&deg[mstU[i]], 1); atomicAdd(&deg[mstV[i]], 1); }
  __syncthreads();
  u32 loc[4]; u32 s = 0;
#pragma unroll
  for (int j = 0; j < 4; ++j){ int v = t*4 + j; u32 d = (v < NL) ? deg[v] : 0; loc[j] = s; s += d; }
  aux[t] = s; __syncthreads();
  for (int st = 1; st < 1024; st <<= 1){
    u32 mine = aux[t]; u32 add = (t >= st) ? aux[t - st] : 0; __syncthreads();
    aux[t] = mine + add; __syncthreads();
  }
  u32 base = (t > 0) ? aux[t-1] : 0;
#pragma unroll
  for (int j = 0; j < 4; ++j){ int v = t*4 + j; if (v < NL) offA[v] = base + loc[j]; }
  if (t == 0) offA[NL] = aux[1023];
  __syncthreads();
  for (int v = t; v < NL; v += NT) deg[v] = offA[v];   // cursor
  __syncthreads();
  for (int i = t; i < nm; i += NT){
    int u = mstU[i], v = mstV[i];
    u32 p1 = atomicAdd(&deg[u], 1); adjl[p1] = (u16)v;
    u32 p2 = atomicAdd(&deg[v], 1); adjl[p2] = (u16)u;
  }
  __syncthreads();

  // BFS from node 0 (level-synchronous; parents unique in a tree -> race-free)
  for (int v = t; v < NL; v += NT) posOf[v] = 0xffffu;
  __syncthreads();
  if (t == 0){
    bfs[0] = 0; ppos[0] = 0; posOf[0] = 0; cnts[1] = 1;
    lvl_g[b*3200 + 0] = 0; lvl_g[b*3200 + 1] = 1;
  }
  __syncthreads();
  int flo = 0, fhi = 1, d = 1;
  while (fhi < NL){
    for (int idx = flo + t; idx < fhi; idx += NT){
      int u = bfs[idx];
      int k0 = offA[u], k1 = offA[u + 1];
      for (int k = k0; k < k1; ++k){
        int v = adjl[k];
        if (posOf[v] == 0xffffu){
          u32 pos = atomicAdd(&cnts[1], 1);
          bfs[pos] = (u16)v; ppos[pos] = (u16)idx; posOf[v] = (u16)pos;
        }
      }
    }
    __syncthreads();
    int nf = (int)cnts[1];
    if (t == 0) lvl_g[b*3200 + d + 1] = nf;
    flo = fhi; fhi = nf; ++d;
    __syncthreads();
    if (nf == flo) break;
  }
  if (t == 0) nlev_g[b] = d;
  for (int p = t; p < NL; p += NT){
    order_g[b*NL + p] = (int)bfs[p];
    parpos_g[b*NL + p] = (int)ppos[p];
  }
}

// ---------- layernorm (wave per row), D in {192} ----------
template<int D>
__global__ __launch_bounds__(256) void ln_kernel(const float* __restrict__ in, const float* __restrict__ g,
                                                 const float* __restrict__ bt, float* __restrict__ out){
  int gw = (int)((blockIdx.x * 256u + threadIdx.x) >> 6);
  int lane = threadIdx.x & 63;
  if (gw >= ROWS) return;
  constexpr int J = D / 64;
  const float* r = in + (size_t)gw * D;
  float v[J]; float s = 0.f;
#pragma unroll
  for (int j = 0; j < J; ++j){ v[j] = r[lane + 64*j]; s += v[j]; }
  s = wredsum(s);
  float mu = s * (1.0f / D);
  float q = 0.f;
#pragma unroll
  for (int j = 0; j < J; ++j){ float dd = v[j] - mu; q += dd*dd; }
  q = wredsum(q);
  float rs = rsqrtf(q * (1.0f / D) + 1e-5f);
  float* o = out + (size_t)gw * D;
#pragma unroll
  for (int j = 0; j < J; ++j){ int dch = lane + 64*j; o[dch] = (v[j] - mu) * rs * g[dch] + bt[dch]; }
}

// ---------- GEMM: C[M,N] = A[M,K] * W[N,K]^T (+bias)(+gelu)(+resid) ----------
template<bool BIAS, int ACT, bool RESID>
__global__ __launch_bounds__(256) void gemm_kernel(
    const float* __restrict__ A, const float* __restrict__ Wm,
    const float* __restrict__ bias, const float* __restrict__ resid,
    float* __restrict__ Cm, int M, int N, int K){
  __shared__ float As[16][68];
  __shared__ float Ws[16][68];
  const int bm = blockIdx.y * 64, bn = blockIdx.x * 64;
  const int tid = threadIdx.x;
  const int lr = tid >> 2, lc = (tid & 3) << 2;
  const int tm = (tid & 15) << 2, tn = (tid >> 4) << 2;
  float acc[4][4] = {};
  for (int k0 = 0; k0 < K; k0 += 16){
    float4 a4 = *(const float4*)(A  + (size_t)(bm + lr) * K + k0 + lc);
    float4 w4 = *(const float4*)(Wm + (size_t)(bn + lr) * K + k0 + lc);
    As[lc+0][lr] = a4.x; As[lc+1][lr] = a4.y; As[lc+2][lr] = a4.z; As[lc+3][lr] = a4.w;
    Ws[lc+0][lr] = w4.x; Ws[lc+1][lr] = w4.y; Ws[lc+2][lr] = w4.z; Ws[lc+3][lr] = w4.w;
    __syncthreads();
#pragma unroll
    for (int k = 0; k < 16; ++k){
      float4 av = *(const float4*)&As[k][tm];
      float4 bv = *(const float4*)&Ws[k][tn];
      acc[0][0] += av.x*bv.x; acc[0][1] += av.x*bv.y; acc[0][2] += av.x*bv.z; acc[0][3] += av.x*bv.w;
      acc[1][0] += av.y*bv.x; acc[1][1] += av.y*bv.y; acc[1][2] += av.y*bv.z; acc[1][3] += av.y*bv.w;
      acc[2][0] += av.z*bv.x; acc[2][1] += av.z*bv.y; acc[2][2] += av.z*bv.z; acc[2][3] += av.z*bv.w;
      acc[3][0] += av.w*bv.x; acc[3][1] += av.w*bv.y; acc[3][2] += av.w*bv.z; acc[3][3] += av.w*bv.w;
    }
    __syncthreads();
  }
#pragma unroll
  for (int i = 0; i < 4; ++i){
    int row = bm + tm + i;
    float4 o;
    float vv[4];
#pragma unroll
    for (int j = 0; j < 4; ++j){
      float v = acc[i][j];
      if (BIAS) v += bias[bn + tn + j];
      if (ACT == 1) v = geluf(v);
      vv[j] = v;
    }
    o.x = vv[0]; o.y = vv[1]; o.z = vv[2]; o.w = vv[3];
    if (RESID){
      float4 rr = *(const float4*)(resid + (size_t)row * N + bn + tn);
      o.x += rr.x; o.y += rr.y; o.z += rr.z; o.w += rr.w;
    }
    *(float4*)(Cm + (size_t)row * N + bn + tn) = o;
  }
}

// ---------- depthwise conv 3x3 SAME + bias + silu ----------
__global__ __launch_bounds__(256) void conv_kernel(const float* __restrict__ xs, const float* __restrict__ cw,
                                                   const float* __restrict__ cb, float* __restrict__ u){
  int idx = blockIdx.x * 256 + threadIdx.x;
  if (idx >= ROWS * 96) return;
  int q = idx % 96; int l = idx / 96;
  int b = l / NL; int hw = l - b * NL; int h = hw / 56; int wc = hw - h * 56;
  int c4 = q * 4;
  float4 acc = *(const float4*)(cb + c4);
#pragma unroll
  for (int kh = 0; kh < 3; ++kh){
    int hh = h + kh - 1; if (hh < 0 || hh >= 56) continue;
#pragma unroll
    for (int kw = 0; kw < 3; ++kw){
      int wwc = wc + kw - 1; if (wwc < 0 || wwc >= 56) continue;
      float4 iv = *(const float4*)(xs + ((size_t)(b * NL + hh*56 + wwc)) * DIN + c4);
      float4 wv = *(const float4*)(cw + (size_t)(kh*3 + kw) * DIN + c4);
      acc.x += iv.x * wv.x; acc.y += iv.y * wv.y; acc.z += iv.z * wv.z; acc.w += iv.w * wv.w;
    }
  }
  float4 o; o.x = siluf(acc.x); o.y = siluf(acc.y); o.z = siluf(acc.z); o.w = siluf(acc.w);
  *(float4*)(u + (size_t)l * DIN + c4) = o;
}

// ---------- x_proj + dt_proj + softplus + w/feat (wave per row) ----------
__global__ __launch_bounds__(256) void xdbl_kernel(const float* __restrict__ u,
    const float* __restrict__ xpw, const float* __restrict__ dtw_g,
    const float* __restrict__ dtb, const float* __restrict__ alog,
    float* __restrict__ wout, float* __restrict__ fout, float* __restrict__ csout){
  __shared__ float xw[14*384];
  __shared__ float dw[384*12];
  __shared__ float db[384];
  __shared__ float An[384];
  int t = threadIdx.x;
  for (int i = t; i < 14*384; i += 256) xw[i] = xpw[i];
  for (int i = t; i < 384*12; i += 256) dw[i] = dtw_g[i];
  for (int i = t; i < 384; i += 256){ db[i] = dtb[i]; An[i] = -expf(alog[i]); }
  __syncthreads();
  int wave = t >> 6, lane = t & 63;
  int row0 = blockIdx.x * 16 + wave * 4;
  for (int rr = 0; rr < 4; ++rr){
    int m = row0 + rr;
    const float* ur = u + (size_t)m * DIN;
    float u6[6];
#pragma unroll
    for (int j = 0; j < 6; ++j) u6[j] = ur[lane + 64*j];
    float xd[14];
#pragma unroll
    for (int r = 0; r < 14; ++r){
      float p = 0.f;
#pragma unroll
      for (int j = 0; j < 6; ++j) p += u6[j] * xw[r*384 + lane + 64*j];
      xd[r] = wredsum(p);
    }
    float Bs = xd[12], Cv = xd[13];
#pragma unroll
    for (int j = 0; j < 6; ++j){
      int dch = lane + 64*j;
      float pre = db[dch];
#pragma unroll
      for (int r = 0; r < 12; ++r) pre += xd[r] * dw[dch*12 + r];
      float dts = sofplus(pre);
      float wv = expf(dts * An[dch]);
      float fv = dts * Bs * u6[j];
      wout[(size_t)m * DIN + dch] = wv;
      fout[(size_t)m * DIN + dch] = fv;
    }
    if (lane == 0) csout[m] = Cv;
  }
}

// ---------- tree sweep: up (leaves->root) then down (root->leaves) ----------
__global__ __launch_bounds__(256) void sweep_kernel(const float* __restrict__ feat, const float* __restrict__ wbuf,
    float* __restrict__ Hout, const int* __restrict__ order_g, const int* __restrict__ parpos_g,
    const int* __restrict__ lvl_g, const int* __restrict__ nlev_g){
  __shared__ float4 S[NL];          // 50176 B
  __shared__ int lvlc[768];         // 3072 B
  int blk = blockIdx.x; int b = blk / 96; int q = blk % 96;
  int t = threadIdx.x;
  int nl = nlev_g[b];
  for (int i = t; i < nl + 1 && i < 768; i += 256) lvlc[i] = lvl_g[b*3200 + i];
  int nodes[13]; int pp[13]; float4 wv[13];
#pragma unroll
  for (int k = 0; k < 13; ++k){
    int p = t + (k << 8);
    if (p < NL){
      int nd = order_g[b*NL + p];
      nodes[k] = nd; pp[k] = parpos_g[b*NL + p];
      size_t base = ((size_t)b * NL + nd) * DIN + q*4;
      S[p] = *(const float4*)&feat[base];
      wv[k] = *(const float4*)&wbuf[base];
    }
  }
  __syncthreads();
  float* Sf = (float*)S;
  for (int d = nl - 1; d >= 1; --d){
    int lo = (d < 768) ? lvlc[d] : lvl_g[b*3200 + d];
    int hi = (d + 1 < 768) ? lvlc[d+1] : lvl_g[b*3200 + d + 1];
#pragma unroll
    for (int k = 0; k < 13; ++k){
      int p = t + (k << 8);
      if (p >= lo && p < hi){
        float4 s = S[p]; float4 w = wv[k]; int par = pp[k];
        atomicAdd(&Sf[par*4 + 0], w.x * s.x);
        atomicAdd(&Sf[par*4 + 1], w.y * s.y);
        atomicAdd(&Sf[par*4 + 2], w.z * s.z);
        atomicAdd(&Sf[par*4 + 3], w.w * s.w);
      }
    }
    __syncthreads();
  }
  for (int d = 1; d < nl; ++d){
    int lo = (d < 768) ? lvlc[d] : lvl_g[b*3200 + d];
    int hi = (d + 1 < 768) ? lvlc[d+1] : lvl_g[b*3200 + d + 1];
#pragma unroll
    for (int k = 0; k < 13; ++k){
      int p = t + (k << 8);
      if (p >= lo && p < hi){
        float4 s = S[p]; float4 w = wv[k]; float4 h = S[pp[k]];
        float4 r;
        r.x = s.x + w.x * (h.x - w.x * s.x);
        r.y = s.y + w.y * (h.y - w.y * s.y);
        r.z = s.z + w.z * (h.z - w.z * s.z);
        r.w = s.w + w.w * (h.w - w.w * s.w);
        S[p] = r;
      }
    }
    __syncthreads();
  }
#pragma unroll
  for (int k = 0; k < 13; ++k){
    int p = t + (k << 8);
    if (p < NL){
      size_t base = ((size_t)b * NL + nodes[k]) * DIN + q*4;
      *(float4*)&Hout[base] = S[p];
    }
  }
}

// ---------- y = Cs*H + Ds*u -> LN -> * silu(z) (wave per row) ----------
__global__ __launch_bounds__(256) void ynorm_kernel(const float* __restrict__ Hh, const float* __restrict__ u,
    const float* __restrict__ z, const float* __restrict__ Cs,
    const float* __restrict__ Ds, const float* __restrict__ g, const float* __restrict__ bt,
    float* __restrict__ out){
  int gw = (int)((blockIdx.x * 256u + threadIdx.x) >> 6);
  int lane = threadIdx.x & 63;
  if (gw >= ROWS) return;
  float Cv = Cs[gw];
  const float* hr = Hh + (size_t)gw * DIN;
  const float* ur = u + (size_t)gw * DIN;
  const float* zr = z + (size_t)gw * DIN;
  float y[6]; float s = 0.f;
#pragma unroll
  for (int j = 0; j < 6; ++j){
    int dch = lane + 64*j;
    y[j] = Cv * hr[dch] + Ds[dch] * ur[dch];
    s += y[j];
  }
  s = wredsum(s);
  float mu = s * (1.0f / DIN);
  float q = 0.f;
#pragma unroll
  for (int j = 0; j < 6; ++j){ float dd = y[j] - mu; q += dd*dd; }
  q = wredsum(q);
  float rs = rsqrtf(q * (1.0f / DIN) + 1e-5f);
  float* o = out + (size_t)gw * DIN;
#pragma unroll
  for (int j = 0; j < 6; ++j){
    int dch = lane + 64*j;
    float yn = (y[j] - mu) * rs * g[dch] + bt[dch];
    o[dch] = yn * siluf(zr[dch]);
  }
}

// ---------- host orchestration ----------
extern "C" void kernel_launch(void* const* d_in, const int* in_sizes, int n_in,
                              void* d_out, int out_size, void* d_ws, size_t ws_size,
                              hipStream_t stream){
  const float* x_in       = (const float*)d_in[0];
  const float* norm1_w    = (const float*)d_in[1];
  const float* norm1_b    = (const float*)d_in[2];
  const float* in_proj_w  = (const float*)d_in[3];
  const float* conv_w     = (const float*)d_in[4];
  const float* conv_b     = (const float*)d_in[5];
  const float* x_proj_w   = (const float*)d_in[6];
  const float* dt_proj_w  = (const float*)d_in[7];
  const float* dt_proj_b  = (const float*)d_in[8];
  const float* A_log      = (const float*)d_in[9];
  const float* Ds         = (const float*)d_in[10];
  const float* out_norm_w = (const float*)d_in[11];
  const float* out_norm_b = (const float*)d_in[12];
  const float* out_proj_w = (const float*)d_in[13];
  const float* norm2_w    = (const float*)d_in[14];
  const float* norm2_b    = (const float*)d_in[15];
  const float* fc1_w      = (const float*)d_in[16];
  const float* fc1_b      = (const float*)d_in[17];
  const float* fc2_w      = (const float*)d_in[18];
  const float* fc2_b      = (const float*)d_in[19];
  const float* fnorm_w    = (const float*)d_in[20];
  const float* fnorm_b    = (const float*)d_in[21];

  float* ws = (float*)d_ws;
  float* X    = ws + 0;          // 4816896  (current x)
  float* bufA = ws + 4816896;    // 4816896  (xn / h)
  float* bufZ = ws + 9633792;    // 9633792  (z)
  float* bufU = ws + 19267584;   // 9633792  (u)
  float* bufF = ws + 28901376;   // 9633792  (xs_preconv / feat / H)
  float* bufW = ws + 38535168;   // 9633792  (w / yln)
  float* Csb  = ws + 48168960;   // 25088
  int*   ordg = (int*)(ws + 48194048);   // 8*3136
  int*   ppg  = (int*)(ws + 48219136);   // 8*3136
  int*   lvlg = (int*)(ws + 48244224);   // 8*3200
  int*   nlvg = (int*)(ws + 48269824);   // 8
  u64*   keysg= (u64*)(ws + 48269832);   // 8*6160 u64
  float* nrm  = ws + 48368392;   // 25088
  float* G    = bufU;            // fc1 out spans bufU+bufF (25088*768)

  hipMemcpyAsync(X, x_in, (size_t)ROWS * NC * sizeof(float), hipMemcpyDeviceToDevice, stream);

  for (int i = 0; i < 2; ++i){
    // tree from current x
    norms_kernel<<<ROWS/4, 256, 0, stream>>>(X, nrm);
    keys_kernel<<<(NB*NE)/4, 256, 0, stream>>>(X, nrm, keysg);
    tree_kernel<<<NB, 1024, 0, stream>>>(keysg, ordg, ppg, lvlg, nlvg);

    // norm1 + in_proj (split xs / z)
    ln_kernel<192><<<ROWS/4, 256, 0, stream>>>(X, norm1_w + i*NC, norm1_b + i*NC, bufA);
    gemm_kernel<false,0,false><<<dim3(6,392), 256, 0, stream>>>(bufA, in_proj_w + (size_t)i*NHID*NC,            nullptr, nullptr, bufF, ROWS, 384, 192);
    gemm_kernel<false,0,false><<<dim3(6,392), 256, 0, stream>>>(bufA, in_proj_w + (size_t)i*NHID*NC + 384*NC,   nullptr, nullptr, bufZ, ROWS, 384, 192);

    // depthwise conv + silu -> u
    conv_kernel<<<(ROWS*96)/256, 256, 0, stream>>>(bufF, conv_w + (size_t)i*9*DIN, conv_b + i*DIN, bufU);

    // x_proj / dt_proj / w,feat,Cs
    xdbl_kernel<<<ROWS/16, 256, 0, stream>>>(bufU, x_proj_w + (size_t)i*14*DIN, dt_proj_w + (size_t)i*DIN*12,
                                             dt_proj_b + i*DIN, A_log + i*DIN, bufW, bufF, Csb);

    // tree scan: feat,w -> H (in place over feat)
    sweep_kernel<<<NB*96, 256, 0, stream>>>(bufF, bufW, bufF, ordg, ppg, lvlg, nlvg);

    // y = Cs*H + Ds*u -> LN -> *silu(z) -> yln (bufW)
    ynorm_kernel<<<ROWS/4, 256, 0, stream>>>(bufF, bufU, bufZ, Csb, Ds + i*DIN,
                                             out_norm_w + i*DIN, out_norm_b + i*DIN, bufW);

    // x += yln @ out_proj^T
    gemm_kernel<false,0,true><<<dim3(3,392), 256, 0, stream>>>(bufW, out_proj_w + (size_t)i*NC*DIN, nullptr, X, X, ROWS, 192, 384);

    // MLP
    ln_kernel<192><<<ROWS/4, 256, 0, stream>>>(X, norm2_w + i*NC, norm2_b + i*NC, bufA);
    gemm_kernel<true,1,false><<<dim3(12,392), 256, 0, stream>>>(bufA, fc1_w + (size_t)i*NHID*NC, fc1_b + i*NHID, nullptr, G, ROWS, NHID, 192);
    gemm_kernel<true,0,true><<<dim3(3,392), 256, 0, stream>>>(G, fc2_w + (size_t)i*NC*NHID, fc2_b + i*NC, X, X, ROWS, 192, NHID);
  }

  // final layernorm -> out
  ln_kernel<192><<<ROWS/4, 256, 0, stream>>>(X, fnorm_w, fnorm_b, (float*)d_out);
}

// Round 2
// 2045.640 us; speedup vs baseline: 1.1991x; 1.1991x over previous
//
#include <hip/hip_runtime.h>
#include <math.h>

#define NB 8
#define NC 192
#define DIN 384
#define NL 3136
#define ROWS (NB*NL)     // 25088
#define NE 6160
#define NHID 768

typedef unsigned short u16;
typedef unsigned int u32;
typedef unsigned long long u64;
typedef __attribute__((ext_vector_type(8))) short bh8;
typedef __attribute__((ext_vector_type(4))) float f4;

// ---------- helpers ----------
__device__ __forceinline__ float wredsum(float v){
  v += __shfl_xor(v, 1, 64); v += __shfl_xor(v, 2, 64); v += __shfl_xor(v, 4, 64);
  v += __shfl_xor(v, 8, 64); v += __shfl_xor(v, 16, 64); v += __shfl_xor(v, 32, 64);
  return v;
}
__device__ __forceinline__ void edge_decode(int e, int& u, int& v){
  if (e < 3080){ int h = e/55, w = e - h*55; u = h*56 + w; v = u + 1; }
  else { int e2 = e - 3080; int h = e2/56, w = e2 - h*56; u = h*56 + w; v = u + 56; }
}
__device__ __forceinline__ float siluf(float x){ return x / (1.0f + expf(-x)); }
__device__ __forceinline__ float sofplus(float x){ return fmaxf(x, 0.0f) + log1pf(expf(-fabsf(x))); }
__device__ __forceinline__ float geluf(float x){ return 0.5f * x * (1.0f + erff(x * 0.70710678118654752f)); }
__device__ __forceinline__ u16 f2bf(float x){
  u32 u = __float_as_uint(x);
  u32 r = (u + 0x7fffu + ((u >> 16) & 1u)) >> 16;
  return (u16)r;
}
__device__ __forceinline__ float bf2f(u16 h){ return __uint_as_float(((u32)h) << 16); }

// ---------- node norms (wave per node) ----------
__global__ __launch_bounds__(256) void norms_kernel(const float* __restrict__ x, float* __restrict__ nrm){
  int gw = (int)((blockIdx.x * 256u + threadIdx.x) >> 6);
  int lane = threadIdx.x & 63;
  if (gw >= ROWS) return;
  const float* r = x + (size_t)gw * NC;
  float s = 0.f;
#pragma unroll
  for (int j = 0; j < 3; ++j){ float v = r[lane + 64*j]; s += v*v; }
  s = wredsum(s);
  if (lane == 0) nrm[gw] = sqrtf(s) + 1e-8f;
}

// ---------- edge keys (wave per edge) ----------
__global__ __launch_bounds__(256) void keys_kernel(const float* __restrict__ x, const float* __restrict__ nrm,
                                                   u64* __restrict__ keys){
  int gw = (int)((blockIdx.x * 256u + threadIdx.x) >> 6);
  int lane = threadIdx.x & 63;
  if (gw >= NB * NE) return;
  int b = gw / NE, e = gw - b * NE;
  int u, v; edge_decode(e, u, v);
  const float* ru = x + ((size_t)b * NL + u) * NC;
  const float* rv = x + ((size_t)b * NL + v) * NC;
  float s = 0.f;
#pragma unroll
  for (int j = 0; j < 3; ++j){ s += ru[lane + 64*j] * rv[lane + 64*j]; }
  s = wredsum(s);
  if (lane == 0){
    float cosv = s / (nrm[b*NL + u] * nrm[b*NL + v]);
    float wgt = expf(1.0f - cosv);
    keys[(size_t)b*NE + e] = ((u64)__float_as_uint(wgt) << 32) | (u64)(u32)e;
  }
}

// ---------- per-image: Boruvka MST + CSR + BFS levels ----------
__global__ __launch_bounds__(1024) void tree_kernel(const u64* __restrict__ keys_g,
      int* __restrict__ order_g, int* __restrict__ parpos_g,
      int* __restrict__ lvl_g, int* __restrict__ nlev_g){
  __shared__ __align__(16) char sm[62736];
  const int b = blockIdx.x;
  const int t = threadIdx.x;
  const int NT = 1024;
  u64* best   = (u64*)sm;            // [3136]  (phase B)
  u16* parent = (u16*)(sm + 25088);
  u16* comp   = (u16*)(sm + 31360);
  u16* mstU   = (u16*)(sm + 37632);
  u16* mstV   = (u16*)(sm + 43904);
  u16* adjl   = (u16*)(sm + 50176);  // [6270]
  u32* cnts   = (u32*)(sm + 62720);  // [4]
  u32* deg    = (u32*)sm;            // [3136]
  u32* offA   = (u32*)(sm + 12544);  // [3137]
  u32* aux    = (u32*)(sm + 25096);  // [1024]
  u16* bfs    = (u16*)sm;            // [3136] (phase D)
  u16* ppos   = (u16*)(sm + 6272);   // [3136]
  u16* posOf  = (u16*)(sm + 29192);  // [3136]

  const u64* kb = keys_g + (size_t)b * NE;
  for (int v = t; v < NL; v += NT) parent[v] = (u16)v;
  if (t == 0) cnts[0] = 0;
  __syncthreads();

  for (int round = 0; round < 24; ++round){
    for (int it = 0; it < 12; ++it){
      for (int v = t; v < NL; v += NT) parent[v] = parent[parent[v]];
      __syncthreads();
    }
    for (int v = t; v < NL; v += NT){ comp[v] = parent[v]; best[v] = ~0ull; }
    if (t == 0) cnts[2] = 0;
    __syncthreads();
    for (int e = t; e < NE; e += NT){
      int u, v; edge_decode(e, u, v);
      u16 ru = comp[u], rv = comp[v];
      if (ru != rv){
        u64 k = kb[e];
        atomicMin(&best[ru], k);
        atomicMin(&best[rv], k);
      }
    }
    __syncthreads();
    for (int r = t; r < NL; r += NT){
      if (comp[r] == (u16)r){
        u64 bk = best[r];
        if (bk != ~0ull){
          int e = (int)(u32)bk; int u, v; edge_decode(e, u, v);
          u16 ru = comp[u], rv = comp[v];
          u16 other = (ru == (u16)r) ? rv : ru;
          bool mutual = (best[other] == bk);
          if (!mutual || (u16)r < other){
            parent[r] = other;
            u32 id = atomicAdd(&cnts[0], 1);
            mstU[id] = (u16)u; mstV[id] = (u16)v;
            cnts[2] = 1;
          }
        }
      }
    }
    __syncthreads();
    if (cnts[0] >= (u32)(NL - 1) || cnts[2] == 0) break;
  }
  __syncthreads();

  const int nm = NL - 1;
  for (int v = t; v < NL; v += NT) deg[v] = 0;
  __syncthreads();
  for (int i = t; i < nm; i += NT){ atomicAdd(&deg[mstU[i]], 1); atomicAdd(&deg[mstV[i]], 1); }
  __syncthreads();
  u32 loc[4]; u32 s = 0;
#pragma unroll
  for (int j = 0; j < 4; ++j){ int v = t*4 + j; u32 d = (v < NL) ? deg[v] : 0; loc[j] = s; s += d; }
  aux[t] = s; __syncthreads();
  for (int st = 1; st < 1024; st <<= 1){
    u32 mine = aux[t]; u32 add = (t >= st) ? aux[t - st] : 0; __syncthreads();
    aux[t] = mine + add; __syncthreads();
  }
  u32 base = (t > 0) ? aux[t-1] : 0;
#pragma unroll
  for (int j = 0; j < 4; ++j){ int v = t*4 + j; if (v < NL) offA[v] = base + loc[j]; }
  if (t == 0) offA[NL] = aux[1023];
  __syncthreads();
  for (int v = t; v < NL; v += NT) deg[v] = offA[v];
  __syncthreads();
  for (int i = t; i < nm; i += NT){
    int u = mstU[i], v = mstV[i];
    u32 p1 = atomicAdd(&deg[u], 1); adjl[p1] = (u16)v;
    u32 p2 = atomicAdd(&deg[v], 1); adjl[p2] = (u16)u;
  }
  __syncthreads();

  for (int v = t; v < NL; v += NT) posOf[v] = 0xffffu;
  __syncthreads();
  if (t == 0){
    bfs[0] = 0; ppos[0] = 0; posOf[0] = 0; cnts[1] = 1;
    lvl_g[b*3200 + 0] = 0; lvl_g[b*3200 + 1] = 1;
  }
  __syncthreads();
  int flo = 0, fhi = 1, d = 1;
  while (fhi < NL){
    for (int idx = flo + t; idx < fhi; idx += NT){
      int u = bfs[idx];
      int k0 = offA[u], k1 = offA[u + 1];
      for (int k = k0; k < k1; ++k){
        int v = adjl[k];
        if (posOf[v] == 0xffffu){
          u32 pos = atomicAdd(&cnts[1], 1);
          bfs[pos] = (u16)v; ppos[pos] = (u16)idx; posOf[v] = (u16)pos;
        }
      }
    }
    __syncthreads();
    int nf = (int)cnts[1];
    if (t == 0) lvl_g[b*3200 + d + 1] = nf;
    flo = fhi; fhi = nf; ++d;
    __syncthreads();
    if (nf == flo) break;
  }
  if (t == 0) nlev_g[b] = d;
  for (int p = t; p < NL; p += NT){
    order_g[b*NL + p] = (int)bfs[p];
    parpos_g[b*NL + p] = (int)ppos[p];
  }
}

// ---------- layernorm (wave per row); SPLIT -> bf16 hi|lo pair output ----------
template<int D, bool SPLIT>
__global__ __launch_bounds__(256) void ln_kernel(const float* __restrict__ in, const float* __restrict__ g,
                                                 const float* __restrict__ bt, void* __restrict__ outv){
  int gw = (int)((blockIdx.x * 256u + threadIdx.x) >> 6);
  int lane = threadIdx.x & 63;
  if (gw >= ROWS) return;
  constexpr int J = D / 64;
  const float* r = in + (size_t)gw * D;
  float v[J]; float s = 0.f;
#pragma unroll
  for (int j = 0; j < J; ++j){ v[j] = r[lane + 64*j]; s += v[j]; }
  s = wredsum(s);
  float mu = s * (1.0f / D);
  float q = 0.f;
#pragma unroll
  for (int j = 0; j < J; ++j){ float dd = v[j] - mu; q += dd*dd; }
  q = wredsum(q);
  float rs = rsqrtf(q * (1.0f / D) + 1e-5f);
  if (SPLIT){
    u16* o = (u16*)outv + (size_t)gw * (2*D);
#pragma unroll
    for (int j = 0; j < J; ++j){
      int dch = lane + 64*j;
      float y = (v[j] - mu) * rs * g[dch] + bt[dch];
      u16 hi = f2bf(y);
      o[dch] = hi; o[D + dch] = f2bf(y - bf2f(hi));
    }
  } else {
    float* o = (float*)outv + (size_t)gw * D;
#pragma unroll
    for (int j = 0; j < J; ++j){ int dch = lane + 64*j; o[dch] = (v[j] - mu) * rs * g[dch] + bt[dch]; }
  }
}

// ---------- weight split fp32 [N,K] -> bf16 [N, hi(K)|lo(K)] ----------
__global__ __launch_bounds__(256) void wsplit_kernel(const float* __restrict__ W, u16* __restrict__ o, int N, int K){
  int i = blockIdx.x * 256 + threadIdx.x;
  if (i >= N * K) return;
  int r = i / K, c = i - r * K;
  float v = W[i];
  u16 hi = f2bf(v);
  o[(size_t)r * 2 * K + c] = hi;
  o[(size_t)r * 2 * K + K + c] = f2bf(v - bf2f(hi));
}

// ---------- MFMA GEMM: C[M,N] = A'[M,2K] * W'[N,2K]^T via hi/lo split ----------
// A' cols [0,K)=hi, [K,2K)=lo. Product = hi*hi + hi*lo + lo*hi.
template<int BN, bool BIAS, int ACT, bool RESID, bool OSPLIT>
__global__ __launch_bounds__(256) void mgemm_kernel(
    const u16* __restrict__ Ap, const u16* __restrict__ Wp,
    const float* __restrict__ bias, const float* __restrict__ resid,
    float* __restrict__ Cm, int M, int N, int K){
  static_assert(BN == 64 || BN == 128, "BN");
  constexpr int WT = (BN == 128) ? 64 : 32;
  constexpr int NF = WT / 16;
  __shared__ short Ah[128*64], Al[128*64];
  __shared__ short Wh[BN*64], Wl[BN*64];
  const int bm = blockIdx.y * 128, bn = blockIdx.x * BN;
  const int tid = threadIdx.x, lane = tid & 63, wid = tid >> 6;
  const int wr = wid >> 1, wc = wid & 1;
  const int K2 = 2 * K;
  f4 acc[4][NF];
#pragma unroll
  for (int mf = 0; mf < 4; ++mf)
#pragma unroll
    for (int nf = 0; nf < NF; ++nf) acc[mf][nf] = (f4){0.f,0.f,0.f,0.f};

  for (int k0 = 0; k0 < K; k0 += 64){
    // stage A tiles (hi & lo), 128 rows x 64 cols, chunk-swizzled
#pragma unroll
    for (int j = 0; j < 4; ++j){
      int q = tid + 256*j; int r = q >> 3, c = q & 7;
      const short* gh = (const short*)Ap + (size_t)(bm + r) * K2 + k0 + c*8;
      bh8 vh = *(const bh8*)gh;
      bh8 vl = *(const bh8*)(gh + K);
      int cs = ((c ^ (r & 7)) * 8);
      *(bh8*)&Ah[r*64 + cs] = vh;
      *(bh8*)&Al[r*64 + cs] = vl;
    }
#pragma unroll
    for (int j = 0; j < BN/32; ++j){
      int q = tid + 256*j; int r = q >> 3, c = q & 7;
      const short* gh = (const short*)Wp + (size_t)(bn + r) * K2 + k0 + c*8;
      bh8 vh = *(const bh8*)gh;
      bh8 vl = *(const bh8*)(gh + K);
      int cs = ((c ^ (r & 7)) * 8);
      *(bh8*)&Wh[r*64 + cs] = vh;
      *(bh8*)&Wl[r*64 + cs] = vl;
    }
    __syncthreads();
#pragma unroll
    for (int kk = 0; kk < 2; ++kk){
      bh8 whf[NF], wlf[NF], ahf[4], alf[4];
#pragma unroll
      for (int nf = 0; nf < NF; ++nf){
        int rw = wc*WT + nf*16 + (lane & 15);
        int c = kk*4 + (lane >> 4);
        int ad = rw*64 + ((c ^ (rw & 7)) * 8);
        whf[nf] = *(const bh8*)&Wh[ad];
        wlf[nf] = *(const bh8*)&Wl[ad];
      }
#pragma unroll
      for (int mf = 0; mf < 4; ++mf){
        int ra = wr*64 + mf*16 + (lane & 15);
        int c = kk*4 + (lane >> 4);
        int ad = ra*64 + ((c ^ (ra & 7)) * 8);
        ahf[mf] = *(const bh8*)&Ah[ad];
        alf[mf] = *(const bh8*)&Al[ad];
      }
#pragma unroll
      for (int mf = 0; mf < 4; ++mf)
#pragma unroll
        for (int nf = 0; nf < NF; ++nf){
          acc[mf][nf] = __builtin_amdgcn_mfma_f32_16x16x32_bf16(ahf[mf], whf[nf], acc[mf][nf], 0, 0, 0);
          acc[mf][nf] = __builtin_amdgcn_mfma_f32_16x16x32_bf16(ahf[mf], wlf[nf], acc[mf][nf], 0, 0, 0);
          acc[mf][nf] = __builtin_amdgcn_mfma_f32_16x16x32_bf16(alf[mf], whf[nf], acc[mf][nf], 0, 0, 0);
        }
    }
    __syncthreads();
  }
  // epilogue: C/D layout col=lane&15, row=(lane>>4)*4+r
  const int cb = bn + wc*WT;
#pragma unroll
  for (int mf = 0; mf < 4; ++mf){
    int row = bm + wr*64 + mf*16 + (lane >> 4)*4;
#pragma unroll
    for (int nf = 0; nf < NF; ++nf){
      int col = cb + nf*16 + (lane & 15);
#pragma unroll
      for (int r = 0; r < 4; ++r){
        float v = acc[mf][nf][r];
        if (BIAS) v += bias[col];
        if (ACT == 1) v = geluf(v);
        if (RESID) v += resid[(size_t)(row + r) * N + col];
        if (OSPLIT){
          u16* Gp = (u16*)Cm;
          u16 hi = f2bf(v);
          Gp[(size_t)(row + r) * (2*N) + col] = hi;
          Gp[(size_t)(row + r) * (2*N) + N + col] = f2bf(v - bf2f(hi));
        } else {
          Cm[(size_t)(row + r) * N + col] = v;
        }
      }
    }
  }
}

// ---------- depthwise conv 3x3 SAME + bias + silu ----------
__global__ __launch_bounds__(256) void conv_kernel(const float* __restrict__ xs, const float* __restrict__ cw,
                                                   const float* __restrict__ cb, float* __restrict__ u){
  int idx = blockIdx.x * 256 + threadIdx.x;
  if (idx >= ROWS * 96) return;
  int q = idx % 96; int l = idx / 96;
  int b = l / NL; int hw = l - b * NL; int h = hw / 56; int wc = hw - h * 56;
  int c4 = q * 4;
  float4 acc = *(const float4*)(cb + c4);
#pragma unroll
  for (int kh = 0; kh < 3; ++kh){
    int hh = h + kh - 1; if (hh < 0 || hh >= 56) continue;
#pragma unroll
    for (int kw = 0; kw < 3; ++kw){
      int wwc = wc + kw - 1; if (wwc < 0 || wwc >= 56) continue;
      float4 iv = *(const float4*)(xs + ((size_t)(b * NL + hh*56 + wwc)) * DIN + c4);
      float4 wv = *(const float4*)(cw + (size_t)(kh*3 + kw) * DIN + c4);
      acc.x += iv.x * wv.x; acc.y += iv.y * wv.y; acc.z += iv.z * wv.z; acc.w += iv.w * wv.w;
    }
  }
  float4 o; o.x = siluf(acc.x); o.y = siluf(acc.y); o.z = siluf(acc.z); o.w = siluf(acc.w);
  *(float4*)(u + (size_t)l * DIN + c4) = o;
}

// ---------- x_proj + dt_proj + softplus + w/feat (wave per row) ----------
__global__ __launch_bounds__(256) void xdbl_kernel(const float* __restrict__ u,
    const float* __restrict__ xpw, const float* __restrict__ dtw_g,
    const float* __restrict__ dtb, const float* __restrict__ alog,
    float* __restrict__ wout, float* __restrict__ fout, float* __restrict__ csout){
  __shared__ float xw[14*384];
  __shared__ float dw[384*12];
  __shared__ float db[384];
  __shared__ float An[384];
  int t = threadIdx.x;
  for (int i = t; i < 14*384; i += 256) xw[i] = xpw[i];
  for (int i = t; i < 384*12; i += 256) dw[i] = dtw_g[i];
  for (int i = t; i < 384; i += 256){ db[i] = dtb[i]; An[i] = -expf(alog[i]); }
  __syncthreads();
  int wave = t >> 6, lane = t & 63;
  int row0 = blockIdx.x * 16 + wave * 4;
  for (int rr = 0; rr < 4; ++rr){
    int m = row0 + rr;
    const float* ur = u + (size_t)m * DIN;
    float u6[6];
#pragma unroll
    for (int j = 0; j < 6; ++j) u6[j] = ur[lane + 64*j];
    float xd[14];
#pragma unroll
    for (int r = 0; r < 14; ++r){
      float p = 0.f;
#pragma unroll
      for (int j = 0; j < 6; ++j) p += u6[j] * xw[r*384 + lane + 64*j];
      xd[r] = wredsum(p);
    }
    float Bs = xd[12], Cv = xd[13];
#pragma unroll
    for (int j = 0; j < 6; ++j){
      int dch = lane + 64*j;
      float pre = db[dch];
#pragma unroll
      for (int r = 0; r < 12; ++r) pre += xd[r] * dw[dch*12 + r];
      float dts = sofplus(pre);
      float wv = expf(dts * An[dch]);
      float fv = dts * Bs * u6[j];
      wout[(size_t)m * DIN + dch] = wv;
      fout[(size_t)m * DIN + dch] = fv;
    }
    if (lane == 0) csout[m] = Cv;
  }
}

// ---------- tree sweep ----------
__global__ __launch_bounds__(256) void sweep_kernel(const float* __restrict__ feat, const float* __restrict__ wbuf,
    float* __restrict__ Hout, const int* __restrict__ order_g, const int* __restrict__ parpos_g,
    const int* __restrict__ lvl_g, const int* __restrict__ nlev_g){
  __shared__ float4 S[NL];
  __shared__ int lvlc[768];
  int blk = blockIdx.x; int b = blk / 96; int q = blk % 96;
  int t = threadIdx.x;
  int nl = nlev_g[b];
  for (int i = t; i < nl + 1 && i < 768; i += 256) lvlc[i] = lvl_g[b*3200 + i];
  int nodes[13]; int pp[13]; float4 wv[13];
#pragma unroll
  for (int k = 0; k < 13; ++k){
    int p = t + (k << 8);
    if (p < NL){
      int nd = order_g[b*NL + p];
      nodes[k] = nd; pp[k] = parpos_g[b*NL + p];
      size_t base = ((size_t)b * NL + nd) * DIN + q*4;
      S[p] = *(const float4*)&feat[base];
      wv[k] = *(const float4*)&wbuf[base];
    }
  }
  __syncthreads();
  float* Sf = (float*)S;
  for (int d = nl - 1; d >= 1; --d){
    int lo = (d < 768) ? lvlc[d] : lvl_g[b*3200 + d];
    int hi = (d + 1 < 768) ? lvlc[d+1] : lvl_g[b*3200 + d + 1];
#pragma unroll
    for (int k = 0; k < 13; ++k){
      int p = t + (k << 8);
      if (p >= lo && p < hi){
        float4 s = S[p]; float4 w = wv[k]; int par = pp[k];
        atomicAdd(&Sf[par*4 + 0], w.x * s.x);
        atomicAdd(&Sf[par*4 + 1], w.y * s.y);
        atomicAdd(&Sf[par*4 + 2], w.z * s.z);
        atomicAdd(&Sf[par*4 + 3], w.w * s.w);
      }
    }
    __syncthreads();
  }
  for (int d = 1; d < nl; ++d){
    int lo = (d < 768) ? lvlc[d] : lvl_g[b*3200 + d];
    int hi = (d + 1 < 768) ? lvlc[d+1] : lvl_g[b*3200 + d + 1];
#pragma unroll
    for (int k = 0; k < 13; ++k){
      int p = t + (k << 8);
      if (p >= lo && p < hi){
        float4 s = S[p]; float4 w = wv[k]; float4 h = S[pp[k]];
        float4 r;
        r.x = s.x + w.x * (h.x - w.x * s.x);
        r.y = s.y + w.y * (h.y - w.y * s.y);
        r.z = s.z + w.z * (h.z - w.z * s.z);
        r.w = s.w + w.w * (h.w - w.w * s.w);
        S[p] = r;
      }
    }
    __syncthreads();
  }
#pragma unroll
  for (int k = 0; k < 13; ++k){
    int p = t + (k << 8);
    if (p < NL){
      size_t base = ((size_t)b * NL + nodes[k]) * DIN + q*4;
      *(float4*)&Hout[base] = S[p];
    }
  }
}

// ---------- y = Cs*H + Ds*u -> LN -> * silu(z) -> bf16 hi|lo pair ----------
__global__ __launch_bounds__(256) void ynorm_kernel(const float* __restrict__ Hh, const float* __restrict__ u,
    const float* __restrict__ z, const float* __restrict__ Cs,
    const float* __restrict__ Ds, const float* __restrict__ g, const float* __restrict__ bt,
    u16* __restrict__ out){
  int gw = (int)((blockIdx.x * 256u + threadIdx.x) >> 6);
  int lane = threadIdx.x & 63;
  if (gw >= ROWS) return;
  float Cv = Cs[gw];
  const float* hr = Hh + (size_t)gw * DIN;
  const float* ur = u + (size_t)gw * DIN;
  const float* zr = z + (size_t)gw * DIN;
  float y[6]; float s = 0.f;
#pragma unroll
  for (int j = 0; j < 6; ++j){
    int dch = lane + 64*j;
    y[j] = Cv * hr[dch] + Ds[dch] * ur[dch];
    s += y[j];
  }
  s = wredsum(s);
  float mu = s * (1.0f / DIN);
  float q = 0.f;
#pragma unroll
  for (int j = 0; j < 6; ++j){ float dd = y[j] - mu; q += dd*dd; }
  q = wredsum(q);
  float rs = rsqrtf(q * (1.0f / DIN) + 1e-5f);
  u16* o = out + (size_t)gw * (2*DIN);
#pragma unroll
  for (int j = 0; j < 6; ++j){
    int dch = lane + 64*j;
    float yn = (y[j] - mu) * rs * g[dch] + bt[dch];
    float v = yn * siluf(zr[dch]);
    u16 hi = f2bf(v);
    o[dch] = hi; o[DIN + dch] = f2bf(v - bf2f(hi));
  }
}

// ---------- host orchestration ----------
extern "C" void kernel_launch(void* const* d_in, const int* in_sizes, int n_in,
                              void* d_out, int out_size, void* d_ws, size_t ws_size,
                              hipStream_t stream){
  const float* x_in       = (const float*)d_in[0];
  const float* norm1_w    = (const float*)d_in[1];
  const float* norm1_b    = (const float*)d_in[2];
  const float* in_proj_w  = (const float*)d_in[3];
  const float* conv_w     = (const float*)d_in[4];
  const float* conv_b     = (const float*)d_in[5];
  const float* x_proj_w   = (const float*)d_in[6];
  const float* dt_proj_w  = (const float*)d_in[7];
  const float* dt_proj_b  = (const float*)d_in[8];
  const float* A_log      = (const float*)d_in[9];
  const float* Ds         = (const float*)d_in[10];
  const float* out_norm_w = (const float*)d_in[11];
  const float* out_norm_b = (const float*)d_in[12];
  const float* out_proj_w = (const float*)d_in[13];
  const float* norm2_w    = (const float*)d_in[14];
  const float* norm2_b    = (const float*)d_in[15];
  const float* fc1_w      = (const float*)d_in[16];
  const float* fc1_b      = (const float*)d_in[17];
  const float* fc2_w      = (const float*)d_in[18];
  const float* fc2_b      = (const float*)d_in[19];
  const float* fnorm_w    = (const float*)d_in[20];
  const float* fnorm_b    = (const float*)d_in[21];

  float* ws = (float*)d_ws;
  float* X     = ws + 0;           // 4816896 f
  u16*   bufAh = (u16*)(ws + 4816896);   // [M, 384] u16 (4816896 f)
  float* bufZ  = ws + 9633792;     // 9633792 f
  float* bufW  = ws + 19267584;    // 9633792 f (w fp32 / yln' u16[M,768])
  float* bufU  = ws + 28901376;    // 9633792 f
  float* bufF  = ws + 38535168;    // 9633792 f
  u16*   Gp    = (u16*)bufU;       // [M,1536] u16 spans bufU+bufF (19267584 f)
  float* Csb   = ws + 48168960;    // 25088
  int*   ordg  = (int*)(ws + 48194048);
  int*   ppg   = (int*)(ws + 48219136);
  int*   lvlg  = (int*)(ws + 48244224);
  int*   nlvg  = (int*)(ws + 48269824);
  u64*   keysg = (u64*)(ws + 48269832);
  float* nrm   = ws + 48368392;
  u16*   ipWp  = (u16*)(ws + 48393480);  // 768x384 u16
  u16*   opWp  = (u16*)(ws + 48540936);  // 192x768 u16
  u16*   fc1Wp = (u16*)(ws + 48614664);  // 768x384 u16
  u16*   fc2Wp = (u16*)(ws + 48762120);  // 192x1536 u16

  hipMemcpyAsync(X, x_in, (size_t)ROWS * NC * sizeof(float), hipMemcpyDeviceToDevice, stream);

  for (int i = 0; i < 2; ++i){
    // split weights -> bf16 hi/lo
    wsplit_kernel<<<(768*192+255)/256, 256, 0, stream>>>(in_proj_w + (size_t)i*NHID*NC, ipWp, 768, 192);
    wsplit_kernel<<<(192*384+255)/256, 256, 0, stream>>>(out_proj_w + (size_t)i*NC*DIN, opWp, 192, 384);
    wsplit_kernel<<<(768*192+255)/256, 256, 0, stream>>>(fc1_w + (size_t)i*NHID*NC, fc1Wp, 768, 192);
    wsplit_kernel<<<(192*768+255)/256, 256, 0, stream>>>(fc2_w + (size_t)i*NC*NHID, fc2Wp, 192, 768);

    // tree from current x
    norms_kernel<<<ROWS/4, 256, 0, stream>>>(X, nrm);
    keys_kernel<<<(NB*NE)/4, 256, 0, stream>>>(X, nrm, keysg);
    tree_kernel<<<NB, 1024, 0, stream>>>(keysg, ordg, ppg, lvlg, nlvg);

    // norm1 -> bf16 split; in_proj (xs and z halves)
    ln_kernel<192,true><<<ROWS/4, 256, 0, stream>>>(X, norm1_w + i*NC, norm1_b + i*NC, bufAh);
    mgemm_kernel<128,false,0,false,false><<<dim3(3,196), 256, 0, stream>>>(bufAh, ipWp,          nullptr, nullptr, bufF, ROWS, 384, 192);
    mgemm_kernel<128,false,0,false,false><<<dim3(3,196), 256, 0, stream>>>(bufAh, ipWp + 147456, nullptr, nullptr, bufZ, ROWS, 384, 192);

    conv_kernel<<<(ROWS*96)/256, 256, 0, stream>>>(bufF, conv_w + (size_t)i*9*DIN, conv_b + i*DIN, bufU);

    xdbl_kernel<<<ROWS/16, 256, 0, stream>>>(bufU, x_proj_w + (size_t)i*14*DIN, dt_proj_w + (size_t)i*DIN*12,
                                             dt_proj_b + i*DIN, A_log + i*DIN, bufW, bufF, Csb);

    sweep_kernel<<<NB*96, 256, 0, stream>>>(bufF, bufW, bufF, ordg, ppg, lvlg, nlvg);

    // y -> LN -> *silu(z) -> bf16 split (into bufW)
    ynorm_kernel<<<ROWS/4, 256, 0, stream>>>(bufF, bufU, bufZ, Csb, Ds + i*DIN,
                                             out_norm_w + i*DIN, out_norm_b + i*DIN, (u16*)bufW);

    // x += yln @ out_proj^T
    mgemm_kernel<64,false,0,true,false><<<dim3(3,196), 256, 0, stream>>>((u16*)bufW, opWp, nullptr, X, X, ROWS, 192, 384);

    // MLP
    ln_kernel<192,true><<<ROWS/4, 256, 0, stream>>>(X, norm2_w + i*NC, norm2_b + i*NC, bufAh);
    mgemm_kernel<128,true,1,false,true><<<dim3(6,196), 256, 0, stream>>>(bufAh, fc1Wp, fc1_b + i*NHID, nullptr, (float*)Gp, ROWS, NHID, 192);
    mgemm_kernel<64,true,0,true,false><<<dim3(3,196), 256, 0, stream>>>(Gp, fc2Wp, fc2_b + i*NC, X, X, ROWS, 192, 768);
  }

  ln_kernel<192,false><<<ROWS/4, 256, 0, stream>>>(X, fnorm_w, fnorm_b, d_out);
}